// Round 3
// baseline (318.169 us; speedup 1.0000x reference)
//
#include <hip/hip_runtime.h>
#include <hip/hip_bf16.h>

// PatchAttentionLayer R9: ONE persistent kernel (grid 256 = 1 block/CU) with
// manual device-scope grid barriers between phases. 2 dispatches total
// (tiny memset of the barrier counter + mono kernel).
//   Phase 0: gram (192 active) + Ghat zeroing  [R8 math unchanged]
//   Phase A: reduce partials -> Gbf/Ghat/S/xbar (385 virtual -> 256 real)
//   Phase B: BN stats (192 active)
//   Phase C: fused matvecs per batch (8 active): u,w,y,r,hb,offv
//   Phase D: fused GEMM chain Z->F->T per (b, 64-col slice) (32 active),
//            Z and F live only in XOR-swizzled LDS (64 KB), mode-1 epilogue -> Tbf
//   Phase E: out = T x + off (512 virtual -> 256 real)
// Barriers: monotone atomic counter, atomicAdd polling (device-scope, cross-XCD
// safe), __threadfence release/acquire, bounded spin (fail-visible, no hang).

#define BB 8
#define CC 256
#define NPIX 4096
#define PTOT 32768
#define EPSV 1e-5f
#define SCALEV 0.125f

// ---- workspace layout (float offsets) ----
#define OFF_PG    0L          // 192*16384 gram partials
#define OFF_SP    3145728L    // rowsum partials
#define OFF_S     3162112L
#define OFF_GHAT  3164160L
#define OFF_XBAR  3229696L
#define OFF_WP    3229952L
#define OFF_WKTF  3426560L
#define OFF_WVTF  3492096L
#define OFF_CVEC  3557632L
#define OFF_U     3558400L
#define OFF_HB    3562496L
#define OFF_R     3564800L
#define OFF_OFFV  3565056L
#define OFF_GBF   3567104L    // 8*65536 ushort
#define OFF_WQT   3829248L
#define OFF_WKT   3862016L
#define OFF_WVB   3894784L
#define OFF_TBF   4222464L    // 8*65536 ushort
#define OFF_CNT   4484608L    // barrier counter (16 floats reserved)

typedef __attribute__((ext_vector_type(8))) short short8;
typedef __attribute__((ext_vector_type(4))) float f32x4;

#define MFMA16(a, b, c) __builtin_amdgcn_mfma_f32_16x16x32_bf16((a), (b), (c), 0, 0, 0)

__device__ __forceinline__ ushort f2bf(float f) {
    union { float f; unsigned u; } v; v.f = f;
    const unsigned r = (v.u + 0x7FFFu + ((v.u >> 16) & 1u)) >> 16;
    return (ushort)r;
}

__device__ __forceinline__ float bf2f(ushort u) {
    union { unsigned u; float f; } v; v.u = ((unsigned)u) << 16;
    return v.f;
}

__device__ __forceinline__ ushort2 f2bf2(float a, float b) {
    __hip_bfloat162 h = __float22bfloat162_rn(float2{a, b});
    union { __hip_bfloat162 h; ushort2 u; } v; v.h = h;
    return v.u;
}

__device__ __forceinline__ float block_reduce(float v, float* red, int tid) {
    red[tid] = v; __syncthreads();
    for (int st = 128; st > 0; st >>= 1) {
        if (tid < st) red[tid] += red[tid + st];
        __syncthreads();
    }
    float r = red[0]; __syncthreads();
    return r;
}

__device__ __forceinline__ float2 wred2(float a, float b, float* red8, int tid) {
    #pragma unroll
    for (int s = 32; s > 0; s >>= 1) {
        a += __shfl_xor(a, s);
        b += __shfl_xor(b, s);
    }
    if ((tid & 63) == 0) { red8[(tid >> 6) * 2] = a; red8[(tid >> 6) * 2 + 1] = b; }
    __syncthreads();
    const float ra = red8[0] + red8[2] + red8[4] + red8[6];
    const float rb = red8[1] + red8[3] + red8[5] + red8[7];
    __syncthreads();
    return float2{ra, rb};
}

// device-scope grid barrier: monotone counter, target = phase_idx * gridDim.
// Poll with atomicAdd(cnt,0) (device-scope read; volatile loads can see a
// stale per-XCD L2 line). Bounded spin: a bug fails visibly, never hangs.
__device__ __forceinline__ void gbar(unsigned* cnt, unsigned target) {
    __syncthreads();
    if (threadIdx.x == 0) {
        __threadfence();
        atomicAdd(cnt, 1u);
        unsigned spins = 0;
        while (atomicAdd(cnt, 0u) < target && ++spins < (1u << 18))
            __builtin_amdgcn_s_sleep(32);
        __threadfence();
    }
    __syncthreads();
}

union SmemU {
    struct { ushort Ab[128 * 72]; ushort Bb[128 * 72]; float rs[128]; } g; // 37.4 KB
    struct { float tile[32][33]; } rm;                                     // 4.2 KB
    struct { float wr4[4][256]; float red8[8]; } st;                       // 4.1 KB
    struct { float sh[256], wl[256], yl[256], gyl[256],
                   red[256], cqs[256], cks[256]; } vx;                     // 7 KB
    struct { ushort zt[64 * 256]; ushort ft[64 * 256]; } ch;               // 64 KB
    struct { ushort Bs[64 * 264]; } op;                                    // 33.8 KB
};

// 256x64 MFMA tile: D[row,col] = sum_k A[row,k]*B[col,k], 4 waves stacked on
// rows. B from global (row-major, stride 256) or XOR-swizzled LDS.
__device__ __forceinline__ void mm256x64(f32x4 acc[4][4],
                                         const ushort* __restrict__ Aglob,
                                         const ushort* __restrict__ Bglob,
                                         const ushort* Blds,
                                         int wave, int m, int qq) {
    const int q8 = qq * 8;
    #pragma unroll
    for (int kk = 0; kk < 8; ++kk) {
        short8 af[4], bv[4];
        #pragma unroll
        for (int a = 0; a < 4; ++a)
            af[a] = *(const short8*)&Aglob[(long)(wave * 64 + a * 16 + m) * 256 + kk * 32 + q8];
        #pragma unroll
        for (int q = 0; q < 4; ++q) {
            const int col = q * 16 + m;
            if (Blds) bv[q] = *(const short8*)&Blds[col * 256 + ((kk * 32 + q8) ^ ((col & 7) << 3))];
            else      bv[q] = *(const short8*)&Bglob[(long)col * 256 + kk * 32 + q8];
        }
        #pragma unroll
        for (int a = 0; a < 4; ++a)
            #pragma unroll
            for (int q = 0; q < 4; ++q)
                acc[a][q] = MFMA16(af[a], bv[q], acc[a][q]);
    }
}

// store D (256x64) -> LDS as L[col][row] bf16, XOR-swizzled on the row index.
__device__ __forceinline__ void st_lds(ushort* L, f32x4 acc[4][4],
                                       int wave, int m, int qq) {
    #pragma unroll
    for (int a = 0; a < 4; ++a)
        #pragma unroll
        for (int q = 0; q < 4; ++q) {
            const int col = q * 16 + m;
            const int rowb = wave * 64 + a * 16 + qq * 4;
            const ushort2 p01 = f2bf2(acc[a][q][0], acc[a][q][1]);
            const ushort2 p23 = f2bf2(acc[a][q][2], acc[a][q][3]);
            ushort4 w4; w4.x = p01.x; w4.y = p01.y; w4.z = p23.x; w4.w = p23.y;
            *(ushort4*)&L[col * 256 + (rowb ^ ((col & 7) << 3))] = w4;
        }
}

__global__ __launch_bounds__(256, 2) void mono(
        const float* __restrict__ x,
        const float* __restrict__ Wq, const float* __restrict__ bq,
        const float* __restrict__ gq, const float* __restrict__ betaq,
        const float* __restrict__ Wk, const float* __restrict__ bk,
        const float* __restrict__ gk, const float* __restrict__ betak,
        const float* __restrict__ Wv, const float* __restrict__ bv,
        const float* __restrict__ gv, const float* __restrict__ betav,
        float* __restrict__ out,
        float* __restrict__ Pg, float* __restrict__ Sp, float* __restrict__ S,
        float* __restrict__ Ghat, float* __restrict__ xbar,
        float* __restrict__ Wp, float* __restrict__ WkTf, float* __restrict__ WvTf,
        float* __restrict__ cvec, float* __restrict__ u, float* __restrict__ hb,
        float* __restrict__ r_, float* __restrict__ offv,
        ushort* __restrict__ Gbf, ushort* __restrict__ WqT, ushort* __restrict__ WkT,
        ushort* __restrict__ Wvb, ushort* __restrict__ Tbf,
        unsigned* __restrict__ cnt) {
    __shared__ SmemU sm;
    const int blk = blockIdx.x, tid = threadIdx.x;
    const unsigned NB = gridDim.x;

    // ================= Phase 0: gram (+ Ghat zero) =================
    if (blk < 64) {
        #pragma unroll
        for (int i = 0; i < 4; ++i) Ghat[blk * 1024 + i * 256 + tid] = 0.f;
    }
    if (blk < 192) {
        const int ks = blk & 7, b = (blk >> 3) & 7, tt = blk >> 6;
        const int it = (tt == 1) ? 1 : 0;
        const int jt = (tt == 0) ? 0 : 1;
        const bool diag = (tt < 2);
        const int i0 = it * 128, j0 = jt * 128, k0 = ks * 512;
        const float* xb = x + (long)b * CC * NPIX;
        const int c = tid & 15, rp = tid >> 4;
        const int wave = tid >> 6, lane = tid & 63;
        const int wr = (wave >> 1) * 64, wc = (wave & 1) * 64;
        const int m = lane & 15, q8 = (lane >> 4) * 8;

        if (tid < 128) sm.g.rs[tid] = 0.f;
        float rloc[8] = {};
        f32x4 acc[4][4];
        #pragma unroll
        for (int a = 0; a < 4; ++a)
            #pragma unroll
            for (int q = 0; q < 4; ++q) acc[a][q] = (f32x4){0.f, 0.f, 0.f, 0.f};

        const float* Abase = xb + (long)i0 * NPIX + k0 + c * 4;
        const float* Bbase = xb + (long)j0 * NPIX + k0 + c * 4;

        float4 va[8], vb[8];
        #pragma unroll
        for (int pp = 0; pp < 8; ++pp)
            va[pp] = *(const float4*)&Abase[(long)(pp * 16 + rp) * NPIX];
        if (!diag) {
            #pragma unroll
            for (int pp = 0; pp < 8; ++pp)
                vb[pp] = *(const float4*)&Bbase[(long)(pp * 16 + rp) * NPIX];
        }

        for (int kc = 0; kc < 512; kc += 64) {
            __syncthreads();
            #pragma unroll
            for (int pp = 0; pp < 8; ++pp) {
                const int row = pp * 16 + rp;
                const float4 v = va[pp];
                rloc[pp] += v.x + v.y + v.z + v.w;
                const ushort2 w01 = f2bf2(v.x, v.y);
                const ushort2 w23 = f2bf2(v.z, v.w);
                ushort4 w; w.x = w01.x; w.y = w01.y; w.z = w23.x; w.w = w23.y;
                *(ushort4*)&sm.g.Ab[row * 72 + c * 4] = w;
            }
            if (!diag) {
                #pragma unroll
                for (int pp = 0; pp < 8; ++pp) {
                    const int row = pp * 16 + rp;
                    const float4 v = vb[pp];
                    const ushort2 w01 = f2bf2(v.x, v.y);
                    const ushort2 w23 = f2bf2(v.z, v.w);
                    ushort4 w; w.x = w01.x; w.y = w01.y; w.z = w23.x; w.w = w23.y;
                    *(ushort4*)&sm.g.Bb[row * 72 + c * 4] = w;
                }
            }
            const int kn = kc + 64;
            if (kn < 512) {
                #pragma unroll
                for (int pp = 0; pp < 8; ++pp)
                    va[pp] = *(const float4*)&Abase[(long)(pp * 16 + rp) * NPIX + kn];
                if (!diag) {
                    #pragma unroll
                    for (int pp = 0; pp < 8; ++pp)
                        vb[pp] = *(const float4*)&Bbase[(long)(pp * 16 + rp) * NPIX + kn];
                }
            }
            __syncthreads();
            const ushort* Bsrc = diag ? sm.g.Ab : sm.g.Bb;
            #pragma unroll
            for (int kk = 0; kk < 2; ++kk) {
                short8 af[4], bfv[4];
                #pragma unroll
                for (int a = 0; a < 4; ++a)
                    af[a] = *(const short8*)&sm.g.Ab[(wr + a * 16 + m) * 72 + kk * 32 + q8];
                #pragma unroll
                for (int q = 0; q < 4; ++q)
                    bfv[q] = *(const short8*)&Bsrc[(wc + q * 16 + m) * 72 + kk * 32 + q8];
                #pragma unroll
                for (int a = 0; a < 4; ++a)
                    #pragma unroll
                    for (int q = 0; q < 4; ++q)
                        acc[a][q] = MFMA16(af[a], bfv[q], acc[a][q]);
            }
        }
        if (diag) {
            #pragma unroll
            for (int pp = 0; pp < 8; ++pp) atomicAdd(&sm.g.rs[pp * 16 + rp], rloc[pp]);
            __syncthreads();
            if (tid < 128) Sp[(((long)ks * 8 + b) * 2 + it) * 128 + tid] = sm.g.rs[tid];
        }
        float* Pt = Pg + (((long)ks * 8 + b) * 3 + tt) * 16384;
        const int rq = (lane >> 4) * 4;
        #pragma unroll
        for (int a = 0; a < 4; ++a) {
            #pragma unroll
            for (int q = 0; q < 4; ++q) {
                const int col = wc + q * 16 + m;
                #pragma unroll
                for (int reg = 0; reg < 4; ++reg)
                    Pt[(long)(wr + a * 16 + rq + reg) * 128 + col] = acc[a][q][reg];
            }
        }
    }
    gbar(cnt, NB * 1);

    // ================= Phase A: reduce partials =================
    for (int v = blk; v <= 384; v += 256) {
        if (v == 384) {
            const int it2 = tid >> 7, rr = tid & 127;
            float xacc = 0.f;
            for (int b = 0; b < BB; ++b) {
                float acc = 0.f;
                #pragma unroll
                for (int ks = 0; ks < 8; ++ks)
                    acc += Sp[(((long)ks * 8 + b) * 2 + it2) * 128 + rr];
                S[b * 256 + tid] = acc;
                xacc += acc;
            }
            xbar[tid] = xacc * (1.0f / PTOT);
            continue;
        }
        const int tt = v >> 7;
        const int sub = (v >> 3) & 15;
        const int b = v & 7;
        const int sr = (sub >> 2) * 32, sc = (sub & 3) * 32;
        const int it = (tt == 1) ? 1 : 0;
        const int jt = (tt == 0) ? 0 : 1;
        const bool offd = (tt == 2);
        const int gi0 = it * 128 + sr, gj0 = jt * 128 + sc;
        const int r = tid >> 3, c4 = (tid & 7) * 4;
        const float inv = 1.0f / PTOT;

        float s0 = 0.f, s1 = 0.f, s2 = 0.f, s3 = 0.f;
        #pragma unroll
        for (int ks = 0; ks < 8; ++ks) {
            const float4 pv = *(const float4*)&Pg[(((long)ks * 8 + b) * 3 + tt) * 16384
                                                  + (long)(sr + r) * 128 + sc + c4];
            s0 += pv.x; s1 += pv.y; s2 += pv.z; s3 += pv.w;
        }
        ushort4 w;
        w.x = f2bf(s0); w.y = f2bf(s1); w.z = f2bf(s2); w.w = f2bf(s3);
        *(ushort4*)&Gbf[(long)b * 65536 + (long)(gi0 + r) * 256 + gj0 + c4] = w;
        float* gd = &Ghat[(long)(gi0 + r) * 256 + gj0 + c4];
        atomicAdd(gd + 0, s0 * inv);
        atomicAdd(gd + 1, s1 * inv);
        atomicAdd(gd + 2, s2 * inv);
        atomicAdd(gd + 3, s3 * inv);
        if (offd) {
            sm.rm.tile[r][c4 + 0] = s0; sm.rm.tile[r][c4 + 1] = s1;
            sm.rm.tile[r][c4 + 2] = s2; sm.rm.tile[r][c4 + 3] = s3;
            __syncthreads();
            const float t0 = sm.rm.tile[c4 + 0][r], t1 = sm.rm.tile[c4 + 1][r];
            const float t2 = sm.rm.tile[c4 + 2][r], t3 = sm.rm.tile[c4 + 3][r];
            ushort4 tw;
            tw.x = f2bf(t0); tw.y = f2bf(t1); tw.z = f2bf(t2); tw.w = f2bf(t3);
            *(ushort4*)&Gbf[(long)b * 65536 + (long)(gj0 + r) * 256 + gi0 + c4] = tw;
            float* gm = &Ghat[(long)(gj0 + r) * 256 + gi0 + c4];
            atomicAdd(gm + 0, t0 * inv);
            atomicAdd(gm + 1, t1 * inv);
            atomicAdd(gm + 2, t2 * inv);
            atomicAdd(gm + 3, t3 * inv);
            __syncthreads();
        }
    }
    gbar(cnt, NB * 2);

    // ================= Phase B: BN stats =================
    if (blk < 192) {
        const int og = blk & 63, t = blk >> 6;
        const int o0 = og * 4;
        const float* Wt  = t == 0 ? Wq : (t == 1 ? Wk : Wv);
        const float* bt  = t == 0 ? bq : (t == 1 ? bk : bv);
        const float* gt  = t == 0 ? gq : (t == 1 ? gk : gv);
        const float* bet = t == 0 ? betaq : (t == 1 ? betak : betav);
        #pragma unroll
        for (int i = 0; i < 4; ++i) sm.st.wr4[i][tid] = Wt[(o0 + i) * 256 + tid];
        const float xb = xbar[tid];
        __syncthreads();
        const float* grow = Ghat + (long)tid * 256;
        float tj[4] = {0.f, 0.f, 0.f, 0.f};
        #pragma unroll 8
        for (int k = 0; k < 256; k += 4) {
            const float4 g = *(const float4*)&grow[k];
            #pragma unroll
            for (int i = 0; i < 4; ++i)
                tj[i] += g.x * sm.st.wr4[i][k]     + g.y * sm.st.wr4[i][k + 1]
                       + g.z * sm.st.wr4[i][k + 2] + g.w * sm.st.wr4[i][k + 3];
        }
        #pragma unroll
        for (int i = 0; i < 4; ++i) {
            const int o = o0 + i;
            const float wv = sm.st.wr4[i][tid];
            const float2 qw = wred2(wv * tj[i], wv * xb, sm.st.red8, tid);
            const float bo = bt[o];
            const float mu = qw.y + bo;
            const float var = qw.x + 2.f * bo * mu - bo * bo - mu * mu;
            const float a = gt[o] * rsqrtf(var + EPSV);
            const float wpv = a * wv;
            Wp[(long)t * 65536 + o * 256 + tid] = wpv;
            const ushort wb = f2bf(wpv);
            if (t == 0) {
                WqT[(long)tid * 256 + o] = wb;
            } else if (t == 1) {
                WkT[(long)tid * 256 + o] = wb;
                WkTf[(long)tid * 256 + o] = wpv;
            } else {
                Wvb[(long)o * 256 + tid] = wb;
                WvTf[(long)tid * 256 + o] = wpv;
            }
            if (tid == 0) cvec[t * 256 + o] = a * (bo - mu) + bet[o];
        }
    }
    gbar(cnt, NB * 3);

    // ================= Phase C: fused matvecs per batch =================
    if (blk < 8) {
        const int b = blk;
        sm.vx.sh[tid]  = S[b * 256 + tid];
        sm.vx.cqs[tid] = cvec[tid];
        sm.vx.cks[tid] = cvec[256 + tid];
        __syncthreads();
        float yy = 0.f, rr = 0.f, uu = 0.f, ww = 0.f;
        #pragma unroll 8
        for (int o = 0; o < 256; ++o) {
            yy += Wp[65536L + (long)o * 256 + tid] * sm.vx.cqs[o];
            rr += Wp[(long)o * 256 + tid] * sm.vx.cks[o];
        }
        #pragma unroll 8
        for (int j = 0; j < 256; ++j) {
            uu += WvTf[(long)j * 256 + tid] * sm.vx.sh[j];
            ww += WkTf[(long)j * 256 + tid] * sm.vx.sh[j];
        }
        sm.vx.yl[tid] = yy; sm.vx.wl[tid] = ww;
        __syncthreads();
        float hh = 0.f, gg = 0.f;
        #pragma unroll 8
        for (int o = 0; o < 256; ++o) {
            hh += Wp[(long)o * 256 + tid] * sm.vx.wl[o];
            gg += bf2f(Gbf[(long)b * 65536 + (long)o * 256 + tid]) * sm.vx.yl[o];
        }
        hb[b * 256 + tid] = hh;
        u[b * 256 + tid] = uu;
        if (blk == 0) r_[tid] = rr;
        sm.vx.gyl[tid] = gg;
        __syncthreads();
        float vg = 0.f;
        #pragma unroll 8
        for (int j = 0; j < 256; ++j) vg += WvTf[(long)j * 256 + tid] * sm.vx.gyl[j];
        const float cv = cvec[512 + tid];
        const float dkq = block_reduce(sm.vx.cqs[tid] * sm.vx.cks[tid], sm.vx.red, tid);
        const float dwq = block_reduce(sm.vx.wl[tid] * sm.vx.cqs[tid], sm.vx.red, tid);
        offv[b * 256 + tid] = SCALEV * (vg + uu * dkq + cv * (dwq + 4096.0f * dkq));
    }
    gbar(cnt, NB * 4);

    // ================= Phase D: fused Z->F->T chain =================
    if (blk < 32) {
        const int b = blk >> 2, j0 = (blk & 3) * 64;
        const int wave = tid >> 6, lane = tid & 63;
        const int m = lane & 15, qq = lane >> 4;
        f32x4 acc[4][4];

        // step 1: zt[jl][k] = Z[k, j0+jl] = sum_o WkT[k,o] * WqT[j0+jl,o]
        #pragma unroll
        for (int a = 0; a < 4; ++a)
            #pragma unroll
            for (int q = 0; q < 4; ++q) acc[a][q] = (f32x4){0.f, 0.f, 0.f, 0.f};
        mm256x64(acc, WkT, WqT + (long)j0 * 256, nullptr, wave, m, qq);
        st_lds(sm.ch.zt, acc, wave, m, qq);
        __syncthreads();

        // step 2: ft[jl][i] = F[i, j0+jl] = sum_k Gbf_b[i,k] * zt[jl][k]
        #pragma unroll
        for (int a = 0; a < 4; ++a)
            #pragma unroll
            for (int q = 0; q < 4; ++q) acc[a][q] = (f32x4){0.f, 0.f, 0.f, 0.f};
        mm256x64(acc, Gbf + (long)b * 65536, nullptr, sm.ch.zt, wave, m, qq);
        st_lds(sm.ch.ft, acc, wave, m, qq);
        __syncthreads();

        // step 3: T[r, j0+jl] = sum_i Wvb[r,i] * ft[jl][i]  (+ mode-1 epilogue)
        #pragma unroll
        for (int a = 0; a < 4; ++a)
            #pragma unroll
            for (int q = 0; q < 4; ++q) acc[a][q] = (f32x4){0.f, 0.f, 0.f, 0.f};
        mm256x64(acc, Wvb, nullptr, sm.ch.ft, wave, m, qq);
        const int rq4 = qq * 4;
        #pragma unroll
        for (int a = 0; a < 4; ++a) {
            #pragma unroll
            for (int q = 0; q < 4; ++q) {
                const int cg = j0 + q * 16 + m;
                const float rv = r_[cg];
                const float t2 = hb[b * 256 + cg] + 4096.0f * rv;
                #pragma unroll
                for (int reg = 0; reg < 4; ++reg) {
                    const int row = wave * 64 + a * 16 + rq4 + reg;
                    const float val = SCALEV * (acc[a][q][reg] + u[b * 256 + row] * rv
                                                + cvec[512 + row] * t2);
                    Tbf[(long)b * 65536 + (long)row * 256 + cg] = f2bf(val);
                }
            }
        }
    }
    gbar(cnt, NB * 5);

    // ================= Phase E: out = T x + off =================
    for (int v = blk; v < 512; v += 256) {
        const int p0 = (v & 63) * 64;
        const int b = v >> 6;
        const float* xb = x + (long)b * CC * NPIX;
        const ushort* Tb = Tbf + (long)b * 65536;
        __syncthreads();

        const int c = tid & 15, kq = tid >> 4;
        #pragma unroll
        for (int kt = 0; kt < 4; ++kt) {
            const int k4 = kt * 64 + kq * 4;
            const int p = c * 4;
            const float4 v0 = *(const float4*)&xb[(long)(k4 + 0) * NPIX + p0 + p];
            const float4 v1 = *(const float4*)&xb[(long)(k4 + 1) * NPIX + p0 + p];
            const float4 v2 = *(const float4*)&xb[(long)(k4 + 2) * NPIX + p0 + p];
            const float4 v3 = *(const float4*)&xb[(long)(k4 + 3) * NPIX + p0 + p];
            ushort2 a01, a23;
            ushort4 w;
            a01 = f2bf2(v0.x, v1.x); a23 = f2bf2(v2.x, v3.x);
            w.x = a01.x; w.y = a01.y; w.z = a23.x; w.w = a23.y;
            *(ushort4*)&sm.op.Bs[(p + 0) * 264 + k4] = w;
            a01 = f2bf2(v0.y, v1.y); a23 = f2bf2(v2.y, v3.y);
            w.x = a01.x; w.y = a01.y; w.z = a23.x; w.w = a23.y;
            *(ushort4*)&sm.op.Bs[(p + 1) * 264 + k4] = w;
            a01 = f2bf2(v0.z, v1.z); a23 = f2bf2(v2.z, v3.z);
            w.x = a01.x; w.y = a01.y; w.z = a23.x; w.w = a23.y;
            *(ushort4*)&sm.op.Bs[(p + 2) * 264 + k4] = w;
            a01 = f2bf2(v0.w, v1.w); a23 = f2bf2(v2.w, v3.w);
            w.x = a01.x; w.y = a01.y; w.z = a23.x; w.w = a23.y;
            *(ushort4*)&sm.op.Bs[(p + 3) * 264 + k4] = w;
        }
        __syncthreads();

        const int wave = tid >> 6, lane = tid & 63;
        const int wr = wave * 64;
        const int m = lane & 15, q8 = (lane >> 4) * 8;
        f32x4 acc[4][4];
        #pragma unroll
        for (int a = 0; a < 4; ++a)
            #pragma unroll
            for (int q = 0; q < 4; ++q) acc[a][q] = (f32x4){0.f, 0.f, 0.f, 0.f};

        #pragma unroll
        for (int kk = 0; kk < 8; ++kk) {
            short8 af[4], bfv[4];
            #pragma unroll
            for (int a = 0; a < 4; ++a)
                af[a] = *(const short8*)&Tb[(long)(wr + a * 16 + m) * 256 + kk * 32 + q8];
            #pragma unroll
            for (int q = 0; q < 4; ++q)
                bfv[q] = *(const short8*)&sm.op.Bs[(q * 16 + m) * 264 + kk * 32 + q8];
            #pragma unroll
            for (int a = 0; a < 4; ++a)
                #pragma unroll
                for (int q = 0; q < 4; ++q)
                    acc[a][q] = MFMA16(af[a], bfv[q], acc[a][q]);
        }

        const int rq = (lane >> 4) * 4;
        #pragma unroll
        for (int a = 0; a < 4; ++a) {
            #pragma unroll
            for (int reg = 0; reg < 4; ++reg) {
                const int row = wr + a * 16 + rq + reg;
                const float off_ = offv[b * CC + row];
                float* orow = &out[((long)b * CC + row) * NPIX + p0];
                #pragma unroll
                for (int q = 0; q < 4; ++q)
                    orow[q * 16 + m] = acc[a][q][reg] + off_;
            }
        }
    }
}

extern "C" void kernel_launch(void* const* d_in, const int* in_sizes, int n_in,
                              void* d_out, int out_size, void* d_ws, size_t ws_size,
                              hipStream_t stream) {
    const float* x     = (const float*)d_in[0];
    const float* Wq    = (const float*)d_in[1];
    const float* bq    = (const float*)d_in[2];
    const float* gq    = (const float*)d_in[3];
    const float* betaq = (const float*)d_in[4];
    const float* Wk    = (const float*)d_in[5];
    const float* bk    = (const float*)d_in[6];
    const float* gk    = (const float*)d_in[7];
    const float* betak = (const float*)d_in[8];
    const float* Wv    = (const float*)d_in[9];
    const float* bv    = (const float*)d_in[10];
    const float* gv    = (const float*)d_in[11];
    const float* betav = (const float*)d_in[12];
    float* ws = (float*)d_ws;

    float*  Pg   = ws + OFF_PG;
    float*  Sp   = ws + OFF_SP;
    float*  S    = ws + OFF_S;
    float*  Ghat = ws + OFF_GHAT;
    float*  Xbar = ws + OFF_XBAR;
    float*  Wp   = ws + OFF_WP;
    float*  WkTf = ws + OFF_WKTF;
    float*  WvTf = ws + OFF_WVTF;
    float*  cvec = ws + OFF_CVEC;
    float*  U    = ws + OFF_U;
    float*  Hb   = ws + OFF_HB;
    float*  R    = ws + OFF_R;
    float*  OffV = ws + OFF_OFFV;
    ushort* Gbf  = (ushort*)(ws + OFF_GBF);
    ushort* WqT  = (ushort*)(ws + OFF_WQT);
    ushort* WkT  = (ushort*)(ws + OFF_WKT);
    ushort* Wvb  = (ushort*)(ws + OFF_WVB);
    ushort* Tbf  = (ushort*)(ws + OFF_TBF);
    unsigned* Cnt = (unsigned*)(ws + OFF_CNT);

    hipMemsetAsync((void*)Cnt, 0, 64, stream);
    mono<<<256, 256, 0, stream>>>(x, Wq, bq, gq, betaq, Wk, bk, gk, betak,
                                  Wv, bv, gv, betav, (float*)d_out,
                                  Pg, Sp, S, Ghat, Xbar, Wp, WkTf, WvTf, cvec,
                                  U, Hb, R, OffV, Gbf, WqT, WkT, Wvb, Tbf, Cnt);
}